// Round 1
// baseline (594.646 us; speedup 1.0000x reference)
//
#include <hip/hip_runtime.h>
#include <cstdint>
#include <cstddef>

typedef __bf16 bf16_t;
typedef __bf16 bf16x8 __attribute__((ext_vector_type(8)));
typedef float f32x4 __attribute__((ext_vector_type(4)));

#define MFMA16(a, b, c) __builtin_amdgcn_mfma_f32_16x16x32_bf16((a), (b), (c), 0, 0, 0)

// ---------------- f32 -> bf16 conversion (RNE), vectorized ----------------
__global__ __launch_bounds__(256) void cvt_f32_bf16(const float* __restrict__ src,
                                                    bf16_t* __restrict__ dst, int n4) {
  int stride = gridDim.x * blockDim.x;
  for (int i = blockIdx.x * blockDim.x + threadIdx.x; i < n4; i += stride) {
    float4 v = *(const float4*)(src + (size_t)i * 4);
    ushort4 o;
    o.x = __builtin_bit_cast(unsigned short, (bf16_t)v.x);
    o.y = __builtin_bit_cast(unsigned short, (bf16_t)v.y);
    o.z = __builtin_bit_cast(unsigned short, (bf16_t)v.z);
    o.w = __builtin_bit_cast(unsigned short, (bf16_t)v.w);
    *(ushort4*)(dst + (size_t)i * 4) = o;
  }
}

// ---------------- shared helpers ----------------
__device__ __forceinline__ void gload_lds16(const bf16_t* g, bf16_t* lds) {
  __builtin_amdgcn_global_load_lds(
      (const __attribute__((address_space(1))) unsigned int*)g,
      (__attribute__((address_space(3))) unsigned int*)lds, 16, 0, 0);
}

// tile pitch = 64 bf16 = 128 B per row; 16B granules XOR-swizzled by (row&7)
__device__ __forceinline__ bf16x8 lds_frag(const bf16_t* tile, int row, int g) {
  int byte = row * 128 + ((g ^ (row & 7)) << 4);
  return *(const bf16x8*)((const char*)tile + byte);
}

// ---------------- GEMM: C[M,N] = A[M,K] * B[N,K]^T, bf16 in, f32 acc ------
// 128x128 tile, BK=64, 4 waves (2x2), per-wave 64x64 = 4x4 MFMA subtiles.
// EPI=0: scatter QKV epilogue (N=3072). EPI=1: plain f32 C (N=1024).
template <int EPI>
__global__ __launch_bounds__(256)
void gemm_bt(const bf16_t* __restrict__ A, const bf16_t* __restrict__ Bm,
             bf16_t* __restrict__ Qo, bf16_t* __restrict__ Ko,
             bf16_t* __restrict__ Vto, float* __restrict__ Co) {
  const int K = 1024;
  __shared__ bf16_t As[128 * 64];
  __shared__ bf16_t Bs[128 * 64];
  const int wave = threadIdx.x >> 6, lane = threadIdx.x & 63;
  const int lm = lane & 15, lg = lane >> 4;
  const int wm = wave >> 1, wn = wave & 1;
  const int tm = blockIdx.y * 128, tn = blockIdx.x * 128;

  f32x4 zero = {0.f, 0.f, 0.f, 0.f};
  f32x4 acc[4][4];
#pragma unroll
  for (int i = 0; i < 4; ++i)
#pragma unroll
    for (int j = 0; j < 4; ++j) acc[i][j] = zero;

  const int srow = lane >> 3;  // row-within-chunk 0..7
  const int gs = lane & 7;     // LDS granule slot 0..7

  for (int k0 = 0; k0 < K; k0 += 64) {
#pragma unroll
    for (int c = 0; c < 4; ++c) {
      int cc = wave * 4 + c;          // chunk 0..15 (8 rows x 128B = 1KB)
      int row = cc * 8 + srow;        // tile row 0..127
      int gsrc = gs ^ (row & 7);      // inverse-swizzled global granule
      gload_lds16(A + (size_t)(tm + row) * K + k0 + gsrc * 8, &As[cc * 512]);
      gload_lds16(Bm + (size_t)(tn + row) * K + k0 + gsrc * 8, &Bs[cc * 512]);
    }
    __syncthreads();
#pragma unroll
    for (int kk = 0; kk < 2; ++kk) {
      bf16x8 af[4], bfr[4];
#pragma unroll
      for (int i = 0; i < 4; ++i) af[i] = lds_frag(As, wm * 64 + i * 16 + lm, kk * 4 + lg);
#pragma unroll
      for (int i = 0; i < 4; ++i) bfr[i] = lds_frag(Bs, wn * 64 + i * 16 + lm, kk * 4 + lg);
#pragma unroll
      for (int mi = 0; mi < 4; ++mi)
#pragma unroll
        for (int ni = 0; ni < 4; ++ni)
          acc[mi][ni] = MFMA16(af[mi], bfr[ni], acc[mi][ni]);
    }
    __syncthreads();
  }

#pragma unroll
  for (int mi = 0; mi < 4; ++mi) {
#pragma unroll
    for (int ni = 0; ni < 4; ++ni) {
#pragma unroll
      for (int r = 0; r < 4; ++r) {
        int m = tm + wm * 64 + mi * 16 + lg * 4 + r;  // row = (lane>>4)*4+reg
        int n = tn + wn * 64 + ni * 16 + lm;          // col = lane&15
        float v = acc[mi][ni][r];
        if (EPI == 0) {
          // n encodes (which, h, d); m encodes (b, s)
          int which = n >> 10, rem = n & 1023;
          int hh = rem >> 6, d = rem & 63;
          int bb = m >> 11, s = m & 2047;
          size_t bh = (size_t)bb * 16 + hh;
          if (which == 0)      Qo[(bh * 2048 + s) * 64 + d] = (bf16_t)v;
          else if (which == 1) Ko[(bh * 2048 + s) * 64 + d] = (bf16_t)v;
          else                 Vto[(bh * 64 + d) * 2048 + s] = (bf16_t)v;  // V transposed
        } else {
          Co[(size_t)m * 1024 + n] = v;
        }
      }
    }
  }
}

// ---------------- causal flash attention -----------------
// grid: (S/64, B*H), 4 waves/block, wave owns 16 q-rows. KV tile = 64.
// Q,K layout [B,H,S,64]; V transposed [B,H,64,S]; out [B,S,H*64] bf16.
__global__ __launch_bounds__(256)
void attn_fwd(const bf16_t* __restrict__ Q, const bf16_t* __restrict__ K,
              const bf16_t* __restrict__ Vt, bf16_t* __restrict__ Aout) {
  const int S = 2048;
  const int qtile = blockIdx.x;
  const int bh = blockIdx.y;
  const int b = bh >> 4, h = bh & 15;
  const int wave = threadIdx.x >> 6, lane = threadIdx.x & 63;
  const int lm = lane & 15, lg = lane >> 4;
  const int qrow0 = qtile * 64 + wave * 16;

  const bf16_t* Qb = Q + (size_t)bh * S * 64;
  const bf16_t* Kb = K + (size_t)bh * S * 64;
  const bf16_t* Vb = Vt + (size_t)bh * 64 * S;

  __shared__ bf16_t Plds[4][16 * 64];  // per-wave P tile, swizzled granules
  bf16_t* P = Plds[wave];

  bf16x8 aq[2];
  aq[0] = *(const bf16x8*)(Qb + (size_t)(qrow0 + lm) * 64 + lg * 8);
  aq[1] = *(const bf16x8*)(Qb + (size_t)(qrow0 + lm) * 64 + 32 + lg * 8);

  float m_run[4], l_run[4];
  f32x4 zero = {0.f, 0.f, 0.f, 0.f};
  f32x4 accO[4];
#pragma unroll
  for (int r = 0; r < 4; ++r) { m_run[r] = -3.0e38f; l_run[r] = 0.f; }
#pragma unroll
  for (int nd = 0; nd < 4; ++nd) accO[nd] = zero;

  const float SC = 0.18033688011112042f;  // log2(e) / sqrt(64)

  for (int t = 0; t <= qtile; ++t) {
    const int kv0 = t * 64;
    f32x4 sacc[4];
#pragma unroll
    for (int nt = 0; nt < 4; ++nt) {
      sacc[nt] = zero;
#pragma unroll
      for (int kk = 0; kk < 2; ++kk) {
        bf16x8 bk = *(const bf16x8*)(Kb + (size_t)(kv0 + nt * 16 + lm) * 64 + kk * 32 + lg * 8);
        sacc[nt] = MFMA16(aq[kk], bk, sacc[nt]);
      }
    }
    const bool last = (t == qtile);
    float tv[4][4];
#pragma unroll
    for (int nt = 0; nt < 4; ++nt)
#pragma unroll
      for (int r = 0; r < 4; ++r) {
        float v = sacc[nt][r] * SC;
        if (last && (nt * 16 + lm > wave * 16 + lg * 4 + r)) v = -3.0e38f;
        tv[nt][r] = v;
      }
    // row max within 16-lane group (rows lg*4+r, cols across lanes)
    float mt[4];
#pragma unroll
    for (int r = 0; r < 4; ++r)
      mt[r] = fmaxf(fmaxf(tv[0][r], tv[1][r]), fmaxf(tv[2][r], tv[3][r]));
#pragma unroll
    for (int off = 1; off < 16; off <<= 1)
#pragma unroll
      for (int r = 0; r < 4; ++r) mt[r] = fmaxf(mt[r], __shfl_xor(mt[r], off));
    float sc[4], rs[4];
#pragma unroll
    for (int r = 0; r < 4; ++r) {
      float mn = fmaxf(m_run[r], mt[r]);
      sc[r] = exp2f(m_run[r] - mn);
      m_run[r] = mn;
      rs[r] = 0.f;
    }
#pragma unroll
    for (int nt = 0; nt < 4; ++nt)
#pragma unroll
      for (int r = 0; r < 4; ++r) {
        float p = exp2f(tv[nt][r] - m_run[r]);
        rs[r] += p;
        int row = lg * 4 + r, col = nt * 16 + lm;
        int byte = row * 128 + ((((col >> 3) ^ (row & 7)) << 4)) + (col & 7) * 2;
        *(bf16_t*)((char*)P + byte) = (bf16_t)p;
      }
#pragma unroll
    for (int off = 1; off < 16; off <<= 1)
#pragma unroll
      for (int r = 0; r < 4; ++r) rs[r] += __shfl_xor(rs[r], off);
#pragma unroll
    for (int r = 0; r < 4; ++r) l_run[r] = l_run[r] * sc[r] + rs[r];
#pragma unroll
    for (int nd = 0; nd < 4; ++nd)
#pragma unroll
      for (int r = 0; r < 4; ++r) accO[nd][r] *= sc[r];
    // drain P writes before reading fragments (same wave, no barrier needed)
    asm volatile("s_waitcnt lgkmcnt(0)" ::: "memory");
#pragma unroll
    for (int kk2 = 0; kk2 < 2; ++kk2) {
      bf16x8 ap = lds_frag(P, lm, kk2 * 4 + lg);
#pragma unroll
      for (int nd = 0; nd < 4; ++nd) {
        bf16x8 bv = *(const bf16x8*)(Vb + (size_t)(nd * 16 + lm) * S + kv0 + kk2 * 32 + lg * 8);
        accO[nd] = MFMA16(ap, bv, accO[nd]);
      }
    }
  }

#pragma unroll
  for (int nd = 0; nd < 4; ++nd)
#pragma unroll
    for (int r = 0; r < 4; ++r) {
      float o = accO[nd][r] / l_run[r];
      size_t idx = ((size_t)(b * 2048 + qrow0 + lg * 4 + r)) * 1024 + h * 64 + nd * 16 + lm;
      Aout[idx] = (bf16_t)o;
    }
}

// ---------------- launch -----------------
extern "C" void kernel_launch(void* const* d_in, const int* in_sizes, int n_in,
                              void* d_out, int out_size, void* d_ws, size_t ws_size,
                              hipStream_t stream) {
  (void)in_sizes; (void)n_in; (void)out_size; (void)ws_size;
  const float* x  = (const float*)d_in[0];
  const float* Wq = (const float*)d_in[1];
  const float* Wk = (const float*)d_in[2];
  const float* Wv = (const float*)d_in[3];
  const float* Wo = (const float*)d_in[4];

  char* w = (char*)d_ws;
  bf16_t* xb    = (bf16_t*)(w);                 // 8192x1024      (16 MiB)
  bf16_t* wb    = (bf16_t*)(w + 16777216);      // 3072x1024      (6 MiB)
  bf16_t* wob   = (bf16_t*)(w + 23068672);      // 1024x1024      (2 MiB)
  bf16_t* qb    = (bf16_t*)(w + 25165824);      // [B,H,S,64]     (16 MiB)
  bf16_t* kb    = (bf16_t*)(w + 41943040);      // [B,H,S,64]     (16 MiB)
  bf16_t* vtb   = (bf16_t*)(w + 58720256);      // [B,H,64,S]     (16 MiB)
  bf16_t* attnb = (bf16_t*)(w + 75497472);      // [B,S,1024]     (16 MiB)

  cvt_f32_bf16<<<512, 256, 0, stream>>>(x, xb, 8388608 / 4);
  cvt_f32_bf16<<<256, 256, 0, stream>>>(Wq, wb, 1048576 / 4);
  cvt_f32_bf16<<<256, 256, 0, stream>>>(Wk, wb + 1048576, 1048576 / 4);
  cvt_f32_bf16<<<256, 256, 0, stream>>>(Wv, wb + 2097152, 1048576 / 4);
  cvt_f32_bf16<<<256, 256, 0, stream>>>(Wo, wob, 1048576 / 4);

  // QKV projection: M=8192, N=3072, K=1024
  gemm_bt<0><<<dim3(24, 64), 256, 0, stream>>>(xb, wb, qb, kb, vtb, nullptr);
  // causal attention
  attn_fwd<<<dim3(32, 64), 256, 0, stream>>>(qb, kb, vtb, attnb);
  // output projection: M=8192, N=1024, K=1024
  gemm_bt<1><<<dim3(8, 64), 256, 0, stream>>>(attnb, wob, nullptr, nullptr, nullptr,
                                              (float*)d_out);
}

// Round 2
// 320.599 us; speedup vs baseline: 1.8548x; 1.8548x over previous
//
#include <hip/hip_runtime.h>
#include <cstdint>
#include <cstddef>

typedef __bf16 bf16_t;
typedef __bf16 bf16x8 __attribute__((ext_vector_type(8)));
typedef float f32x4 __attribute__((ext_vector_type(4)));

#define MFMA16(a, b, c) __builtin_amdgcn_mfma_f32_16x16x32_bf16((a), (b), (c), 0, 0, 0)

// ---------------- f32 -> bf16 conversion (RNE), vectorized ----------------
__global__ __launch_bounds__(256) void cvt_f32_bf16(const float* __restrict__ src,
                                                    bf16_t* __restrict__ dst, int n4) {
  int stride = gridDim.x * blockDim.x;
  for (int i = blockIdx.x * blockDim.x + threadIdx.x; i < n4; i += stride) {
    float4 v = *(const float4*)(src + (size_t)i * 4);
    ushort4 o;
    o.x = __builtin_bit_cast(unsigned short, (bf16_t)v.x);
    o.y = __builtin_bit_cast(unsigned short, (bf16_t)v.y);
    o.z = __builtin_bit_cast(unsigned short, (bf16_t)v.z);
    o.w = __builtin_bit_cast(unsigned short, (bf16_t)v.w);
    *(ushort4*)(dst + (size_t)i * 4) = o;
  }
}

// ---------------- shared helpers ----------------
__device__ __forceinline__ void gload_lds16(const bf16_t* g, bf16_t* lds) {
  __builtin_amdgcn_global_load_lds(
      (const __attribute__((address_space(1))) unsigned int*)g,
      (__attribute__((address_space(3))) unsigned int*)lds, 16, 0, 0);
}

// tile pitch = 64 bf16 = 128 B per row; 16B granules XOR-swizzled by (row&7)
__device__ __forceinline__ bf16x8 lds_frag(const bf16_t* tile, int row, int g) {
  int byte = row * 128 + ((g ^ (row & 7)) << 4);
  return *(const bf16x8*)((const char*)tile + byte);
}

// DPP row_ror reduction within each 16-lane row (VALU latency, no LDS)
template <int CTRL>
__device__ __forceinline__ float dpp_mov(float x) {
  int xi = __builtin_bit_cast(int, x);
  return __builtin_bit_cast(float, __builtin_amdgcn_update_dpp(xi, xi, CTRL, 0xF, 0xF, false));
}
__device__ __forceinline__ float rowred_max(float x) {
  x = fmaxf(x, dpp_mov<0x121>(x));  // row_ror:1
  x = fmaxf(x, dpp_mov<0x122>(x));  // row_ror:2
  x = fmaxf(x, dpp_mov<0x124>(x));  // row_ror:4
  x = fmaxf(x, dpp_mov<0x128>(x));  // row_ror:8
  return x;
}
__device__ __forceinline__ float rowred_sum(float x) {
  x += dpp_mov<0x121>(x);
  x += dpp_mov<0x122>(x);
  x += dpp_mov<0x124>(x);
  x += dpp_mov<0x128>(x);
  return x;
}

// ---------------- GEMM: C[M,N] = A[M,K] * B[N,K]^T, bf16 in, f32 acc ------
template <int EPI>
__global__ __launch_bounds__(256)
void gemm_bt(const bf16_t* __restrict__ A, const bf16_t* __restrict__ Bm,
             bf16_t* __restrict__ Qo, bf16_t* __restrict__ Ko,
             bf16_t* __restrict__ Vto, float* __restrict__ Co) {
  const int K = 1024;
  __shared__ bf16_t As[128 * 64];
  __shared__ bf16_t Bs[128 * 64];
  const int wave = threadIdx.x >> 6, lane = threadIdx.x & 63;
  const int lm = lane & 15, lg = lane >> 4;
  const int wm = wave >> 1, wn = wave & 1;
  const int tm = blockIdx.y * 128, tn = blockIdx.x * 128;

  f32x4 zero = {0.f, 0.f, 0.f, 0.f};
  f32x4 acc[4][4];
#pragma unroll
  for (int i = 0; i < 4; ++i)
#pragma unroll
    for (int j = 0; j < 4; ++j) acc[i][j] = zero;

  const int srow = lane >> 3;
  const int gs = lane & 7;

  for (int k0 = 0; k0 < K; k0 += 64) {
#pragma unroll
    for (int c = 0; c < 4; ++c) {
      int cc = wave * 4 + c;
      int row = cc * 8 + srow;
      int gsrc = gs ^ (row & 7);
      gload_lds16(A + (size_t)(tm + row) * K + k0 + gsrc * 8, &As[cc * 512]);
      gload_lds16(Bm + (size_t)(tn + row) * K + k0 + gsrc * 8, &Bs[cc * 512]);
    }
    __syncthreads();
#pragma unroll
    for (int kk = 0; kk < 2; ++kk) {
      bf16x8 af[4], bfr[4];
#pragma unroll
      for (int i = 0; i < 4; ++i) af[i] = lds_frag(As, wm * 64 + i * 16 + lm, kk * 4 + lg);
#pragma unroll
      for (int i = 0; i < 4; ++i) bfr[i] = lds_frag(Bs, wn * 64 + i * 16 + lm, kk * 4 + lg);
#pragma unroll
      for (int mi = 0; mi < 4; ++mi)
#pragma unroll
        for (int ni = 0; ni < 4; ++ni)
          acc[mi][ni] = MFMA16(af[mi], bfr[ni], acc[mi][ni]);
    }
    __syncthreads();
  }

#pragma unroll
  for (int mi = 0; mi < 4; ++mi) {
#pragma unroll
    for (int ni = 0; ni < 4; ++ni) {
#pragma unroll
      for (int r = 0; r < 4; ++r) {
        int m = tm + wm * 64 + mi * 16 + lg * 4 + r;
        int n = tn + wn * 64 + ni * 16 + lm;
        float v = acc[mi][ni][r];
        if (EPI == 0) {
          int which = n >> 10, rem = n & 1023;
          int hh = rem >> 6, d = rem & 63;
          int bb = m >> 11, s = m & 2047;
          size_t bh = (size_t)bb * 16 + hh;
          if (which == 0)      Qo[(bh * 2048 + s) * 64 + d] = (bf16_t)v;
          else if (which == 1) Ko[(bh * 2048 + s) * 64 + d] = (bf16_t)v;
          else                 Vto[(bh * 64 + d) * 2048 + s] = (bf16_t)v;
        } else {
          Co[(size_t)m * 1024 + n] = v;
        }
      }
    }
  }
}

// ---------------- causal flash attention, paired q-tiles -----------------
// grid: 1024 blocks; block -> (bh, pair p). Tiles tLo=p, tHi=31-p (64 rows
// each), 4 waves, wave owns 16 rows of each tile -> two independent
// online-softmax chains per wave sharing K/V register tiles.
__device__ __forceinline__ void sm_step(f32x4 s[4], float* m_run, float* l_run,
                                        f32x4* acc, bf16_t* P, bool diag,
                                        int lm, int lg, int wrow) {
  const float SC = 0.18033688011112042f;  // log2(e)/sqrt(64)
  float tv[4][4];
#pragma unroll
  for (int nt = 0; nt < 4; ++nt)
#pragma unroll
    for (int r = 0; r < 4; ++r) {
      float v = s[nt][r] * SC;
      if (diag && (nt * 16 + lm > wrow + lg * 4 + r)) v = -3.0e38f;
      tv[nt][r] = v;
    }
  float sc[4];
#pragma unroll
  for (int r = 0; r < 4; ++r) {
    float mt = rowred_max(fmaxf(fmaxf(tv[0][r], tv[1][r]), fmaxf(tv[2][r], tv[3][r])));
    float mn = fmaxf(m_run[r], mt);
    sc[r] = exp2f(m_run[r] - mn);
    m_run[r] = mn;
  }
  float rs[4] = {0.f, 0.f, 0.f, 0.f};
#pragma unroll
  for (int nt = 0; nt < 4; ++nt)
#pragma unroll
    for (int r = 0; r < 4; ++r) {
      float pv = exp2f(tv[nt][r] - m_run[r]);
      rs[r] += pv;
      int row = lg * 4 + r, col = nt * 16 + lm;
      int byte = row * 128 + ((((col >> 3) ^ (row & 7)) << 4)) + (col & 7) * 2;
      *(bf16_t*)((char*)P + byte) = (bf16_t)pv;
    }
#pragma unroll
  for (int r = 0; r < 4; ++r) l_run[r] = l_run[r] * sc[r] + rowred_sum(rs[r]);
#pragma unroll
  for (int nd = 0; nd < 4; ++nd)
#pragma unroll
    for (int r = 0; r < 4; ++r) acc[nd][r] *= sc[r];
}

__device__ __forceinline__ void pv_step(const bf16_t* P, const bf16x8 bv[4][2],
                                        f32x4* acc, int lm, int lg) {
#pragma unroll
  for (int kk2 = 0; kk2 < 2; ++kk2) {
    bf16x8 ap = lds_frag(P, lm, kk2 * 4 + lg);
#pragma unroll
    for (int nd = 0; nd < 4; ++nd) acc[nd] = MFMA16(ap, bv[nd][kk2], acc[nd]);
  }
}

__global__ __launch_bounds__(256, 2)
void attn_fwd(const bf16_t* __restrict__ Q, const bf16_t* __restrict__ K,
              const bf16_t* __restrict__ Vt, bf16_t* __restrict__ Aout) {
  const int S = 2048;
  const int i = blockIdx.x;
  // XCD-locality decode: all 16 pair-blocks of one bh land on the same XCD
  const int bh = (i & 7) * 8 + ((i >> 3) & 7);
  const int p = i >> 6;
  const int tLo = p, tHi = 31 - p;
  const int b = bh >> 4, h = bh & 15;
  const int wave = threadIdx.x >> 6, lane = threadIdx.x & 63;
  const int lm = lane & 15, lg = lane >> 4;
  const int qrowL = tLo * 64 + wave * 16;
  const int qrowH = tHi * 64 + wave * 16;

  const bf16_t* Qb = Q + (size_t)bh * S * 64;
  const bf16_t* Kb = K + (size_t)bh * S * 64;
  const bf16_t* Vb = Vt + (size_t)bh * 64 * S;

  __shared__ bf16_t Plds[4][2][16 * 64];
  bf16_t* PL = Plds[wave][0];
  bf16_t* PH = Plds[wave][1];

  bf16x8 aqL[2], aqH[2];
#pragma unroll
  for (int kk = 0; kk < 2; ++kk) {
    aqL[kk] = *(const bf16x8*)(Qb + (size_t)(qrowL + lm) * 64 + kk * 32 + lg * 8);
    aqH[kk] = *(const bf16x8*)(Qb + (size_t)(qrowH + lm) * 64 + kk * 32 + lg * 8);
  }

  f32x4 zero = {0.f, 0.f, 0.f, 0.f};
  float mL[4], lL[4], mH[4], lH[4];
  f32x4 accL[4], accH[4];
#pragma unroll
  for (int r = 0; r < 4; ++r) { mL[r] = -3.0e38f; lL[r] = 0.f; mH[r] = -3.0e38f; lH[r] = 0.f; }
#pragma unroll
  for (int nd = 0; nd < 4; ++nd) { accL[nd] = zero; accH[nd] = zero; }

  for (int t = 0; t <= tHi; ++t) {
    const int kv0 = t * 64;
    const bool actL = (t <= tLo);
    bf16x8 bk[4][2], bv[4][2];
#pragma unroll
    for (int nt = 0; nt < 4; ++nt)
#pragma unroll
      for (int kk = 0; kk < 2; ++kk) {
        bk[nt][kk] = *(const bf16x8*)(Kb + (size_t)(kv0 + nt * 16 + lm) * 64 + kk * 32 + lg * 8);
        bv[nt][kk] = *(const bf16x8*)(Vb + (size_t)(nt * 16 + lm) * S + kv0 + kk * 32 + lg * 8);
      }
    f32x4 sH[4], sL[4];
#pragma unroll
    for (int nt = 0; nt < 4; ++nt) {
      sH[nt] = zero;
#pragma unroll
      for (int kk = 0; kk < 2; ++kk) sH[nt] = MFMA16(aqH[kk], bk[nt][kk], sH[nt]);
    }
    if (actL) {
#pragma unroll
      for (int nt = 0; nt < 4; ++nt) {
        sL[nt] = zero;
#pragma unroll
        for (int kk = 0; kk < 2; ++kk) sL[nt] = MFMA16(aqL[kk], bk[nt][kk], sL[nt]);
      }
    }
    sm_step(sH, mH, lH, accH, PH, t == tHi, lm, lg, wave * 16);
    if (actL) sm_step(sL, mL, lL, accL, PL, t == tLo, lm, lg, wave * 16);
    asm volatile("s_waitcnt lgkmcnt(0)" ::: "memory");
    pv_step(PH, bv, accH, lm, lg);
    if (actL) pv_step(PL, bv, accL, lm, lg);
  }

#pragma unroll
  for (int nd = 0; nd < 4; ++nd)
#pragma unroll
    for (int r = 0; r < 4; ++r) {
      float oH = accH[nd][r] / lH[r];
      float oL = accL[nd][r] / lL[r];
      size_t colbase = (size_t)(h * 64 + nd * 16 + lm);
      Aout[((size_t)(b * 2048 + qrowH + lg * 4 + r)) * 1024 + colbase] = (bf16_t)oH;
      Aout[((size_t)(b * 2048 + qrowL + lg * 4 + r)) * 1024 + colbase] = (bf16_t)oL;
    }
}

// ---------------- launch -----------------
extern "C" void kernel_launch(void* const* d_in, const int* in_sizes, int n_in,
                              void* d_out, int out_size, void* d_ws, size_t ws_size,
                              hipStream_t stream) {
  (void)in_sizes; (void)n_in; (void)out_size; (void)ws_size;
  const float* x  = (const float*)d_in[0];
  const float* Wq = (const float*)d_in[1];
  const float* Wk = (const float*)d_in[2];
  const float* Wv = (const float*)d_in[3];
  const float* Wo = (const float*)d_in[4];

  char* w = (char*)d_ws;
  bf16_t* xb    = (bf16_t*)(w);                 // 8192x1024      (16 MiB)
  bf16_t* wb    = (bf16_t*)(w + 16777216);      // 3072x1024      (6 MiB)
  bf16_t* wob   = (bf16_t*)(w + 23068672);      // 1024x1024      (2 MiB)
  bf16_t* qb    = (bf16_t*)(w + 25165824);      // [B,H,S,64]     (16 MiB)
  bf16_t* kb    = (bf16_t*)(w + 41943040);      // [B,H,S,64]     (16 MiB)
  bf16_t* vtb   = (bf16_t*)(w + 58720256);      // [B,H,64,S]     (16 MiB)
  bf16_t* attnb = (bf16_t*)(w + 75497472);      // [B,S,1024]     (16 MiB)

  cvt_f32_bf16<<<512, 256, 0, stream>>>(x, xb, 8388608 / 4);
  cvt_f32_bf16<<<256, 256, 0, stream>>>(Wq, wb, 1048576 / 4);
  cvt_f32_bf16<<<256, 256, 0, stream>>>(Wk, wb + 1048576, 1048576 / 4);
  cvt_f32_bf16<<<256, 256, 0, stream>>>(Wv, wb + 2097152, 1048576 / 4);
  cvt_f32_bf16<<<256, 256, 0, stream>>>(Wo, wob, 1048576 / 4);

  // QKV projection: M=8192, N=3072, K=1024
  gemm_bt<0><<<dim3(24, 64), 256, 0, stream>>>(xb, wb, qb, kb, vtb, nullptr);
  // causal attention (paired q-tiles, balanced)
  attn_fwd<<<dim3(1024), 256, 0, stream>>>(qb, kb, vtb, attnb);
  // output projection: M=8192, N=1024, K=1024
  gemm_bt<1><<<dim3(8, 64), 256, 0, stream>>>(attnb, wob, nullptr, nullptr, nullptr,
                                              (float*)d_out);
}